// Round 9
// baseline (155.041 us; speedup 1.0000x reference)
//
#include <hip/hip_runtime.h>
#include <hip/hip_cooperative_groups.h>
#include <cstdint>
#include <cstddef>

namespace cg = cooperative_groups;

typedef unsigned long long u64;
typedef unsigned int u32;
typedef unsigned short u16;

#define N_ 4096
#define MMAX_ 2048   // max candidates per (b,c) pair; actual ~1365
#define KCAP_ 32     // pred-list cap (adj); nms fast path covers dg<=8, slow path to 32
#define SENT_ 2048   // sentinel pred index -> always-dead byte slot

__device__ __forceinline__ float sigf(float x) { return 1.0f / (1.0f + expf(-x)); }

// ---------------- adjacency ball body (verified R6/R8) ------------------------
// Geometric pruning (offsets in open (0,1)):
//   cut=1.0 : two axes at |dcell|=2 give min d2 >= 1.17 > 1.0  -> 80-cell ball
//   cut=0.75: any axis at |dcell|=2 exceeds 0.75 strictly      -> 26-cell ball
// pred(i,j): dist<cut && (okey_i > okey_j || (okey_i==okey_j && n_i < n_j))
// == "i earlier in ref's stable desc-conf sort" (key orientation, label-free).
template <int EXT>
__device__ __forceinline__ void adj_body(
    const float4* __restrict__ posG, const u16* __restrict__ slotG,
    int* __restrict__ deg, u16* __restrict__ predL, int pair, int n, int slot,
    float cut2) {
  float4 self = posG[pair * N_ + n];
  u32 okey = __float_as_uint(self.w);
  int d0 = n >> 10, h0 = (n >> 5) & 31, w0 = n & 31;
  u16* rowp = predL + (((size_t)pair * MMAX_ + slot) << 5);
  int cnt = 0;
  #pragma unroll
  for (int dd = -EXT; dd <= EXT; ++dd) {
    #pragma unroll
    for (int dh = -EXT; dh <= EXT; ++dh) {
      #pragma unroll
      for (int dw = -EXT; dw <= EXT; ++dw) {
        if (dd == 0 && dh == 0 && dw == 0) continue;
        if ((dd * dd == 4) + (dh * dh == 4) + (dw * dw == 4) > 1) continue;
        int d2i = d0 + dd, h2i = h0 + dh, w2i = w0 + dw;
        if ((u32)d2i < 4u && (u32)h2i < 32u && (u32)w2i < 32u) {
          int n2 = (d2i << 10) | (h2i << 5) | w2i;
          float4 pn = posG[pair * N_ + n2];    // invalid -> 1e9 -> dist rejects
          float dx = pn.x - self.x, dy = pn.y - self.y, dz = pn.z - self.z;
          float dsq = dx * dx + dy * dy + dz * dz;
          u32 ok2 = __float_as_uint(pn.w);
          bool pred = (dsq < cut2) && (ok2 > okey || (ok2 == okey && n2 < n));
          if (pred) {
            u16 s2 = slotG[pair * N_ + n2];
            if (cnt < KCAP_) rowp[cnt] = s2;
            cnt++;
          }
        }
      }
    }
  }
  if (cnt > KCAP_) cnt = KCAP_;
  deg[pair * MMAX_ + slot] = cnt;
  int pad = (cnt + 3) & ~3;                    // pad group-of-4 with sentinel
  for (int s = cnt; s < pad; ++s) rowp[s] = (u16)SENT_;
}

// ---------------- match ball body (verified R8) -------------------------------
template <int EXT>
__device__ __forceinline__ int match_ball(
    const float4* __restrict__ alive, int n, float tx, float ty, float tz,
    float cut2) {
  int d0 = n >> 10, h0 = (n >> 5) & 31, w0 = n & 31;
  int m = 0;
  #pragma unroll
  for (int dd = -EXT; dd <= EXT; ++dd) {
    #pragma unroll
    for (int dh = -EXT; dh <= EXT; ++dh) {
      #pragma unroll
      for (int dw = -EXT; dw <= EXT; ++dw) {
        if ((dd * dd == 4) + (dh * dh == 4) + (dw * dw == 4) > 1) continue;
        int d2i = d0 + dd, h2i = h0 + dh, w2i = w0 + dw;
        if ((u32)d2i < 4u && (u32)h2i < 32u && (u32)w2i < 32u) {
          int n2 = (d2i << 10) | (h2i << 5) | w2i;
          float4 p = alive[n2];               // dead -> 1e9 -> dist rejects
          float dx = p.x - tx, dy = p.y - ty, dz = p.z - tz;
          m |= (int)(dx * dx + dy * dy + dz * dz < cut2);
        }
      }
    }
  }
  return m;
}

// any-of-4 over byte array, two u32s each packing two u16 indices
#define ANY4B(arr, wa, wb) \
  ((int)((arr)[(wa) & 0xFFFFu] | (arr)[(wa) >> 16] | \
         (arr)[(wb) & 0xFFFFu] | (arr)[(wb) >> 16]))

// ---------------- fused cooperative kernel ------------------------------------
// P1 compact -> sync -> P2 adjacency -> sync -> P3 NMS fixpoint (blocks 0..3)
// -> sync -> P4 lattice-ball matching. All phase bodies are the R8-verified
// algorithms; only the parallel decomposition changes.
__global__ __launch_bounds__(256) void k_all(
    const float* __restrict__ pc, const float* __restrict__ pb,
    const int* __restrict__ tcls, const float* __restrict__ tb,
    int* __restrict__ cntG, float4* __restrict__ posG, u16* __restrict__ slotG,
    float4* __restrict__ sp4, int* __restrict__ deg, u16* __restrict__ predL,
    float4* __restrict__ alivePosG, int* __restrict__ out) {
  cg::grid_group grid = cg::this_grid();
  int blk = blockIdx.x, tid = threadIdx.x, lane = tid & 63;

  // ---- P1: compact + dense lattice maps (16 blocks per pair, 256 anchors ea.)
  {
    int pair = blk >> 4, b = pair >> 1, c = (pair & 1) + 1;
    int n = ((blk & 15) << 8) | tid;
    const float* pcb = pc + (size_t)b * 3 * N_;
    const float* pbb = pb + (size_t)b * 3 * N_;
    float v0 = pcb[n], v1 = pcb[n + N_], v2 = pcb[n + 2 * N_];
    float cf = v0; int a = 0;
    if (v1 > cf) { cf = v1; a = 1; }
    if (v2 > cf) { cf = v2; a = 2; }
    bool valid = (a == c);
    u32 o = __float_as_uint(cf);
    o ^= (o >> 31) ? 0xFFFFFFFFu : 0x80000000u;   // ascending-orderable conf
    u64 ball = __ballot(valid);
    int wbase = 0;
    if (lane == 0 && ball) wbase = atomicAdd(&cntG[pair], __popcll(ball));
    wbase = __shfl(wbase, 0);
    int p = wbase + __popcll(ball & ((1ull << lane) - 1ull));
    float4 dead; dead.x = 1e9f; dead.y = 1e9f; dead.z = 1e9f; dead.w = 0.f;
    alivePosG[pair * N_ + n] = dead;              // P3 overwrites alive rows
    if (valid && p < MMAX_) {
      float d = (float)(n >> 10), h = (float)((n >> 5) & 31), w = (float)(n & 31);
      // (g+s)/dims*REAL == (g+s)*{0.75,0.78125,0.78125} bit-exactly (pow2 dims)
      float x = (d + sigf(pbb[n])) * 0.75f;
      float y = (h + sigf(pbb[n + N_])) * 0.78125f;
      float z = (w + sigf(pbb[n + 2 * N_])) * 0.78125f;
      float4 vg; vg.x = x; vg.y = y; vg.z = z; vg.w = __uint_as_float(o);
      posG[pair * N_ + n] = vg;
      slotG[pair * N_ + n] = (u16)p;
      float4 vs; vs.x = x; vs.y = y; vs.z = z; vs.w = __uint_as_float((u32)n);
      sp4[pair * MMAX_ + p] = vs;
    } else {
      posG[pair * N_ + n] = dead;
      slotG[pair * N_ + n] = (u16)0xFFFF;
    }
  }
  grid.sync();

  // ---- P2: lattice-ball predecessor adjacency (one thread per anchor)
  {
    int idx = (blk << 8) | tid;
    int pair = idx >> 12, n = idx & (N_ - 1);
    int slot = slotG[pair * N_ + n];
    if (slot != 0xFFFF) {
      if (pair & 1) adj_body<1>(posG, slotG, deg, predL, pair, n, slot, 0.5625f);
      else          adj_body<2>(posG, slotG, deg, predL, pair, n, slot, 1.0f);
    }
  }
  grid.sync();

  // ---- P3: byte-array LDS matrix-NMS fixpoint (blocks 0..3, 8 rows/thread)
  // Per-iteration exactly the ref update; monotone => early break exact.
  __shared__ unsigned char aliveB[2064];  // [2048..] sentinel slots, always 0
  __shared__ unsigned char freeB[2064];
  __shared__ int flag[2], acnt;
  if (blk < 4) {
    int pair = blk;
    int M = cntG[pair]; if (M > MMAX_) M = MMAX_;
    int dg[8]; u32 pw[8][4]; bool al[8];
    #pragma unroll
    for (int q = 0; q < 8; ++q) {
      int r = tid + (q << 8);
      al[q] = (r < M);
      dg[q] = deg[pair * MMAX_ + r];          // garbage when r>=M, guarded
      uint4 t = *(const uint4*)(predL + (((size_t)pair * MMAX_ + r) << 5));
      pw[q][0] = t.x; pw[q][1] = t.y; pw[q][2] = t.z; pw[q][3] = t.w;
      aliveB[r] = al[q];
      freeB[r] = 0;
    }
    if (tid < 16) { aliveB[2048 + tid] = 0; freeB[2048 + tid] = 0; }
    if (tid == 0) { flag[0] = 0; flag[1] = 0; acnt = 0; }
    __syncthreads();
    for (int iter = 0; iter < 32; ++iter) {
      if (tid == 0) flag[(iter + 1) & 1] = 0; // reset NEXT flag (barrier-ordered)
      // stage 1: free = alive && all preds dead
      #pragma unroll
      for (int q = 0; q < 8; ++q) {
        int r = tid + (q << 8);
        bool fr = al[q];
        if (al[q] && dg[q]) {
          int any = ANY4B(aliveB, pw[q][0], pw[q][1]);
          if (dg[q] > 4) any |= ANY4B(aliveB, pw[q][2], pw[q][3]);
          if (dg[q] > 8) {                    // rare: tail from L2-hot predL
            const u16* rowp = predL + (((size_t)pair * MMAX_ + r) << 5);
            for (int k = 8; k < dg[q]; ++k) any |= aliveB[rowp[k]];
          }
          fr = (any == 0);
        }
        freeB[r] = fr;
      }
      __syncthreads();
      // stage 2: alive' = alive && no free pred (monotone: only 1->0)
      int lch = 0;
      #pragma unroll
      for (int q = 0; q < 8; ++q) {
        int r = tid + (q << 8);
        if (al[q] && dg[q]) {
          int any = ANY4B(freeB, pw[q][0], pw[q][1]);
          if (dg[q] > 4) any |= ANY4B(freeB, pw[q][2], pw[q][3]);
          if (dg[q] > 8) {
            const u16* rowp = predL + (((size_t)pair * MMAX_ + r) << 5);
            for (int k = 8; k < dg[q]; ++k) any |= freeB[rowp[k]];
          }
          if (any) { al[q] = false; aliveB[r] = 0; lch = 1; }
        }
      }
      if (lch) flag[iter & 1] = 1;
      __syncthreads();
      if (!flag[iter & 1]) break;             // fixpoint: rest are no-ops
    }
    // epilogue: scatter alive positions to dense anchor map + count
    int cntA = 0;
    #pragma unroll
    for (int q = 0; q < 8; ++q) {
      if (al[q]) {
        cntA++;
        float4 v = sp4[pair * MMAX_ + tid + (q << 8)];
        alivePosG[pair * N_ + (int)__float_as_uint(v.w)] = v;
      }
    }
    if (cntA) atomicAdd(&acnt, cntA);
    __syncthreads();
    if (tid == 0) {
      out[pair * 3 + 0] = 0;        // tp  (P4 adds)
      out[pair * 3 + 1] = acnt;     // fp = A - tp (P4 subtracts)
      out[pair * 3 + 2] = 0;        // fn = t_cls - tp (P4 adds/subtracts)
    }
  }
  grid.sync();

  // ---- P4: lattice-ball target matching (one thread per anchor)
  {
    int idx = (blk << 8) | tid;
    int pair = idx >> 12, n = idx & (N_ - 1);
    int b = pair >> 1, c = (pair & 1) + 1;
    float cut2 = (pair & 1) ? 0.5625f : 1.0f;
    __shared__ int s_tp, s_t;
    if (tid == 0) { s_tp = 0; s_t = 0; }
    __syncthreads();
    int isC = (tcls[b * N_ + n] == c) ? 1 : 0;
    float d = (float)(n >> 10), h = (float)((n >> 5) & 31), w = (float)(n & 31);
    const float* tbp = tb + ((size_t)b * N_ + n) * 3;
    float tx = (d + tbp[0]) * 0.75f;
    float ty = (h + tbp[1]) * 0.78125f;
    float tz = (w + tbp[2]) * 0.78125f;
    const float4* alive = alivePosG + (size_t)pair * N_;
    int m;
    if (pair & 1) m = match_ball<1>(alive, n, tx, ty, tz, cut2);
    else          m = match_ball<2>(alive, n, tx, ty, tz, cut2);
    m &= isC;
    atomicAdd(&s_tp, m);
    atomicAdd(&s_t, isC);
    __syncthreads();
    if (tid == 0) {
      atomicAdd(&out[pair * 3 + 0], s_tp);
      atomicAdd(&out[pair * 3 + 1], -s_tp);
      atomicAdd(&out[pair * 3 + 2], s_t - s_tp);
    }
  }
}

// ------------------------------------------------------------------------------
extern "C" void kernel_launch(void* const* d_in, const int* in_sizes, int n_in,
                              void* d_out, int out_size, void* d_ws, size_t ws_size,
                              hipStream_t stream) {
  (void)in_sizes; (void)n_in; (void)out_size; (void)ws_size;
  const float* pc = (const float*)d_in[0];  // pred_clses (B,3,4,32,32) f32
  const float* pb = (const float*)d_in[1];  // pred_boxes (B,3,4,32,32) f32
  const int*   tc = (const int*)d_in[2];    // targ_clses (B,4,32,32) i32
  const float* tb = (const float*)d_in[3];  // targ_boxes (B,4,32,32,3) f32
  int* out = (int*)d_out;                   // (B, C-1, 1, 3) int32 counts

  char* ws = (char*)d_ws;
  size_t off = 0;
  auto alloc = [&](size_t bytes) -> void* {
    void* p = ws + off;
    off += (bytes + 255) & ~(size_t)255;
    return p;
  };
  int*    cntG      = (int*)alloc(4 * 4);
  float4* posG      = (float4*)alloc((size_t)4 * N_ * 16);
  u16*    slotG     = (u16*)alloc((size_t)4 * N_ * 2);
  float4* sp4       = (float4*)alloc((size_t)4 * MMAX_ * 16);
  int*    deg       = (int*)alloc((size_t)4 * MMAX_ * 4);
  u16*    predL     = (u16*)alloc((size_t)4 * MMAX_ * KCAP_ * 2);
  float4* alivePosG = (float4*)alloc((size_t)4 * N_ * 16);

  hipMemsetAsync(cntG, 0, 4 * sizeof(int), stream);  // ws is 0xAA-poisoned

  void* args[] = {
    (void*)&pc, (void*)&pb, (void*)&tc, (void*)&tb,
    (void*)&cntG, (void*)&posG, (void*)&slotG, (void*)&sp4,
    (void*)&deg, (void*)&predL, (void*)&alivePosG, (void*)&out
  };
  hipLaunchCooperativeKernel((const void*)k_all, dim3(64), dim3(256),
                             args, 0, stream);
}

// Round 10
// 104.727 us; speedup vs baseline: 1.4804x; 1.4804x over previous
//
#include <hip/hip_runtime.h>
#include <cstdint>
#include <cstddef>

typedef unsigned long long u64;
typedef unsigned int u32;
typedef unsigned short u16;

#define N_ 4096
#define MMAX_ 2048   // max candidates per (b,c) pair; actual ~1365
#define KCAP_ 32     // pred-list cap (adj); nms fast path dg<=8, slow tail to 32
#define SENT_ 2048   // sentinel pred index -> always-dead byte slot

__device__ __forceinline__ float sigf(float x) { return 1.0f / (1.0f + expf(-x)); }

// any-of-4 over byte array; wa/wb are u32s each packing two u16 indices
#define ANY4B(arr, wa, wb) \
  ((int)((arr)[(wa) & 0xFFFFu] | (arr)[(wa) >> 16] | \
         (arr)[(wb) & 0xFFFFu] | (arr)[(wb) >> 16]))

// ---------------- K1: compact + dense lattice maps (verified R8) --------------
// One block per (b,c) pair. Writes: slot-indexed sp4[slot]={x,y,z,bitcast(n)},
// dense posG[n]={x,y,z,bitcast(okey)} (invalid -> 1e9, distance self-rejects),
// slotG[n], and initializes alivePosG[n] to dead (k_nms scatters alive rows).
// Sorted order is only needed to ORIENT conflict edges; okey comparison
// reproduces it exactly (see k_adj) -> compaction order is irrelevant.
__global__ __launch_bounds__(1024) void k_compact(
    const float* __restrict__ pc, const float* __restrict__ pb,
    int* __restrict__ Mcnt, float4* __restrict__ posG, u16* __restrict__ slotG,
    float4* __restrict__ sp4, float4* __restrict__ alivePosG) {
  int pair = blockIdx.x, b = pair >> 1, c = (pair & 1) + 1;
  int tid = threadIdx.x, lane = tid & 63;
  __shared__ int cnt;
  if (tid == 0) cnt = 0;
  __syncthreads();
  const float* pcb = pc + (size_t)b * 3 * N_;
  const float* pbb = pb + (size_t)b * 3 * N_;
  for (int base = 0; base < N_; base += 1024) {
    int n = base + tid;
    float v0 = pcb[n], v1 = pcb[n + N_], v2 = pcb[n + 2 * N_];
    float cf = v0; int a = 0;
    if (v1 > cf) { cf = v1; a = 1; }
    if (v2 > cf) { cf = v2; a = 2; }
    bool valid = (a == c);
    u32 o = __float_as_uint(cf);
    o ^= (o >> 31) ? 0xFFFFFFFFu : 0x80000000u;   // ascending-orderable conf
    u64 ball = __ballot(valid);
    int wbase = 0;
    if (lane == 0 && ball) wbase = atomicAdd(&cnt, __popcll(ball));
    wbase = __shfl(wbase, 0);
    int p = wbase + __popcll(ball & ((1ull << lane) - 1ull));
    float4 dead; dead.x = 1e9f; dead.y = 1e9f; dead.z = 1e9f; dead.w = 0.f;
    alivePosG[pair * N_ + n] = dead;              // k_nms overwrites alive rows
    if (valid && p < MMAX_) {
      float d = (float)(n >> 10), h = (float)((n >> 5) & 31), w = (float)(n & 31);
      // (g+s)/dims*REAL == (g+s)*{0.75,0.78125,0.78125} bit-exactly (pow2 dims)
      float x = (d + sigf(pbb[n])) * 0.75f;
      float y = (h + sigf(pbb[n + N_])) * 0.78125f;
      float z = (w + sigf(pbb[n + 2 * N_])) * 0.78125f;
      float4 vg; vg.x = x; vg.y = y; vg.z = z; vg.w = __uint_as_float(o);
      posG[pair * N_ + n] = vg;
      slotG[pair * N_ + n] = (u16)p;
      float4 vs; vs.x = x; vs.y = y; vs.z = z; vs.w = __uint_as_float((u32)n);
      sp4[pair * MMAX_ + p] = vs;
    } else {
      posG[pair * N_ + n] = dead;
      slotG[pair * N_ + n] = (u16)0xFFFF;
    }
  }
  __syncthreads();
  if (tid == 0) {
    int M = cnt; if (M > MMAX_) M = MMAX_;
    Mcnt[pair] = M;
  }
}

// ---------------- K2: lattice-ball predecessor adjacency (verified R6/R8) -----
// One thread per anchor. Geometric pruning (offsets in open (0,1)):
//   cut=1.0 : two axes at |dcell|=2 give min d2 >= 1.17 > 1.0  -> 80-cell ball
//   cut=0.75: any axis at |dcell|=2 exceeds 0.75 strictly      -> 26-cell ball
// pred(i,j): dist<cut && (okey_i > okey_j || (okey_i==okey_j && n_i < n_j))
// == "i earlier in ref's stable desc-conf sort" (key orientation, label-free).
template <int EXT>
__device__ __forceinline__ void adj_body(
    const float4* __restrict__ posG, const u16* __restrict__ slotG,
    int* __restrict__ deg, u16* __restrict__ predL, int pair, int n, int slot,
    float cut2) {
  float4 self = posG[pair * N_ + n];
  u32 okey = __float_as_uint(self.w);
  int d0 = n >> 10, h0 = (n >> 5) & 31, w0 = n & 31;
  u16* rowp = predL + (((size_t)pair * MMAX_ + slot) << 5);
  int cnt = 0;
  #pragma unroll
  for (int dd = -EXT; dd <= EXT; ++dd) {
    #pragma unroll
    for (int dh = -EXT; dh <= EXT; ++dh) {
      #pragma unroll
      for (int dw = -EXT; dw <= EXT; ++dw) {
        if (dd == 0 && dh == 0 && dw == 0) continue;
        if ((dd * dd == 4) + (dh * dh == 4) + (dw * dw == 4) > 1) continue;
        int d2i = d0 + dd, h2i = h0 + dh, w2i = w0 + dw;
        if ((u32)d2i < 4u && (u32)h2i < 32u && (u32)w2i < 32u) {
          int n2 = (d2i << 10) | (h2i << 5) | w2i;
          float4 pn = posG[pair * N_ + n2];    // invalid -> 1e9 -> dist rejects
          float dx = pn.x - self.x, dy = pn.y - self.y, dz = pn.z - self.z;
          float dsq = dx * dx + dy * dy + dz * dz;
          u32 ok2 = __float_as_uint(pn.w);
          bool pred = (dsq < cut2) && (ok2 > okey || (ok2 == okey && n2 < n));
          if (pred) {                          // rare (~2 per row)
            u16 s2 = slotG[pair * N_ + n2];
            if (cnt < KCAP_) rowp[cnt] = s2;
            cnt++;
          }
        }
      }
    }
  }
  if (cnt > KCAP_) cnt = KCAP_;
  deg[pair * MMAX_ + slot] = cnt;
  int pad = (cnt + 3) & ~3;                    // pad group-of-4 with sentinel
  for (int s = cnt; s < pad; ++s) rowp[s] = (u16)SENT_;
}

__global__ __launch_bounds__(256) void k_adj(
    const float4* __restrict__ posG, const u16* __restrict__ slotG,
    int* __restrict__ deg, u16* __restrict__ predL) {
  int idx = blockIdx.x * 256 + threadIdx.x;   // 0..16383
  int pair = idx >> 12, n = idx & (N_ - 1);
  int slot = slotG[pair * N_ + n];
  if (slot == 0xFFFF) return;
  if (pair & 1) adj_body<1>(posG, slotG, deg, predL, pair, n, slot, 0.5625f);
  else          adj_body<2>(posG, slotG, deg, predL, pair, n, slot, 1.0f);
}

// ---------------- K3: byte-array LDS matrix-NMS fixpoint ----------------------
// Per-iteration exactly the ref update:
//   free_i  = alive_i && no alive conflicting predecessor
//   alive'_j = alive_j && no free conflicting predecessor
// Monotone => early break at fixpoint exact; capped at ref's 32 iters.
// Staging: 16B/row fast path (dg<=8, covers ~all rows); dg>8 tail reads
// L2-hot predL directly (logic verified in R9's passing run).
__global__ __launch_bounds__(1024) void k_nms(
    const int* __restrict__ Mcnt, const int* __restrict__ deg,
    const u16* __restrict__ predL, const float4* __restrict__ sp4,
    float4* __restrict__ alivePosG, int* __restrict__ out) {
  int pair = blockIdx.x;
  int tid = threadIdx.x;
  int M = Mcnt[pair];
  __shared__ unsigned char aliveB[2064];  // [2048..] sentinel slots, always 0
  __shared__ unsigned char freeB[2064];
  __shared__ int flag[2], acnt;
  int r0 = tid, r1 = tid + 1024;
  int dg0 = deg[pair * MMAX_ + r0];       // garbage when r>=M, guarded by al
  int dg1 = deg[pair * MMAX_ + r1];
  u32 pw0[4], pw1[4];
  {
    uint4 t0 = *(const uint4*)(predL + (((size_t)pair * MMAX_ + r0) << 5));
    pw0[0] = t0.x; pw0[1] = t0.y; pw0[2] = t0.z; pw0[3] = t0.w;
    uint4 t1 = *(const uint4*)(predL + (((size_t)pair * MMAX_ + r1) << 5));
    pw1[0] = t1.x; pw1[1] = t1.y; pw1[2] = t1.z; pw1[3] = t1.w;
  }
  bool a0 = (r0 < M), a1 = (r1 < M);
  aliveB[r0] = a0; aliveB[r1] = a1;
  freeB[r0] = 0; freeB[r1] = 0;
  if (tid < 16) { aliveB[2048 + tid] = 0; freeB[2048 + tid] = 0; }
  if (tid == 0) { flag[0] = 0; flag[1] = 0; acnt = 0; }
  __syncthreads();

  for (int iter = 0; iter < 32; ++iter) {
    if (tid == 0) flag[(iter + 1) & 1] = 0;  // reset NEXT flag (barrier-ordered)
    // ---- stage 1: free = alive && all preds dead
    bool fr0 = a0, fr1 = a1;
    if (a0 && dg0) {
      int any = ANY4B(aliveB, pw0[0], pw0[1]);
      if (dg0 > 4) any |= ANY4B(aliveB, pw0[2], pw0[3]);
      if (dg0 > 8) {
        const u16* rowp = predL + (((size_t)pair * MMAX_ + r0) << 5);
        for (int k = 8; k < dg0; ++k) any |= aliveB[rowp[k]];
      }
      fr0 = (any == 0);
    }
    if (a1 && dg1) {
      int any = ANY4B(aliveB, pw1[0], pw1[1]);
      if (dg1 > 4) any |= ANY4B(aliveB, pw1[2], pw1[3]);
      if (dg1 > 8) {
        const u16* rowp = predL + (((size_t)pair * MMAX_ + r1) << 5);
        for (int k = 8; k < dg1; ++k) any |= aliveB[rowp[k]];
      }
      fr1 = (any == 0);
    }
    freeB[r0] = fr0; freeB[r1] = fr1;
    __syncthreads();
    // ---- stage 2: alive' = alive && no free pred (monotone: only 1->0)
    int lch = 0;
    if (a0 && dg0) {
      int any = ANY4B(freeB, pw0[0], pw0[1]);
      if (dg0 > 4) any |= ANY4B(freeB, pw0[2], pw0[3]);
      if (dg0 > 8) {
        const u16* rowp = predL + (((size_t)pair * MMAX_ + r0) << 5);
        for (int k = 8; k < dg0; ++k) any |= freeB[rowp[k]];
      }
      if (any) { a0 = false; aliveB[r0] = 0; lch = 1; }
    }
    if (a1 && dg1) {
      int any = ANY4B(freeB, pw1[0], pw1[1]);
      if (dg1 > 4) any |= ANY4B(freeB, pw1[2], pw1[3]);
      if (dg1 > 8) {
        const u16* rowp = predL + (((size_t)pair * MMAX_ + r1) << 5);
        for (int k = 8; k < dg1; ++k) any |= freeB[rowp[k]];
      }
      if (any) { a1 = false; aliveB[r1] = 0; lch = 1; }
    }
    if (lch) flag[iter & 1] = 1;
    __syncthreads();
    if (!flag[iter & 1]) break;              // fixpoint: rest are no-ops
  }

  // scatter alive positions to dense anchor map + count
  if (a0) {
    float4 v = sp4[pair * MMAX_ + r0];
    alivePosG[pair * N_ + (int)__float_as_uint(v.w)] = v;
  }
  if (a1) {
    float4 v = sp4[pair * MMAX_ + r1];
    alivePosG[pair * N_ + (int)__float_as_uint(v.w)] = v;
  }
  {
    u64 ball = __ballot(a0);
    if ((tid & 63) == 0 && ball) atomicAdd(&acnt, __popcll(ball));
  }
  {
    u64 ball = __ballot(a1);
    if ((tid & 63) == 0 && ball) atomicAdd(&acnt, __popcll(ball));
  }
  __syncthreads();
  if (tid == 0) {
    int A = acnt;
    out[pair * 3 + 0] = 0;   // tp  (K4 adds)
    out[pair * 3 + 1] = A;   // fp = A - tp (K4 subtracts)
    out[pair * 3 + 2] = 0;   // fn = t_cls - tp (K4 adds/subtracts)
  }
}

// ---------------- K4: lattice-ball target matching (verified R8) --------------
// One thread per anchor; a matching alive pred lies within the same +/-2 ball
// (target offset in [0,1), pred offset in (0,1)); includes the center cell.
template <int EXT>
__device__ __forceinline__ int match_ball(
    const float4* __restrict__ alive, int n, float tx, float ty, float tz,
    float cut2) {
  int d0 = n >> 10, h0 = (n >> 5) & 31, w0 = n & 31;
  int m = 0;
  #pragma unroll
  for (int dd = -EXT; dd <= EXT; ++dd) {
    #pragma unroll
    for (int dh = -EXT; dh <= EXT; ++dh) {
      #pragma unroll
      for (int dw = -EXT; dw <= EXT; ++dw) {
        if ((dd * dd == 4) + (dh * dh == 4) + (dw * dw == 4) > 1) continue;
        int d2i = d0 + dd, h2i = h0 + dh, w2i = w0 + dw;
        if ((u32)d2i < 4u && (u32)h2i < 32u && (u32)w2i < 32u) {
          int n2 = (d2i << 10) | (h2i << 5) | w2i;
          float4 p = alive[n2];               // dead -> 1e9 -> dist rejects
          float dx = p.x - tx, dy = p.y - ty, dz = p.z - tz;
          m |= (int)(dx * dx + dy * dy + dz * dz < cut2);
        }
      }
    }
  }
  return m;
}

__global__ __launch_bounds__(256) void k_match(
    const float4* __restrict__ alivePosG,
    const int* __restrict__ tcls, const float* __restrict__ tb,
    int* __restrict__ out) {
  int idx = blockIdx.x * 256 + threadIdx.x;   // 0..16383
  int pair = idx >> 12, n = idx & (N_ - 1);
  int b = pair >> 1, c = (pair & 1) + 1;
  float cut2 = (pair & 1) ? 0.5625f : 1.0f;
  __shared__ int s_tp, s_t;
  if (threadIdx.x == 0) { s_tp = 0; s_t = 0; }
  __syncthreads();
  int isC = (tcls[b * N_ + n] == c) ? 1 : 0;
  float d = (float)(n >> 10), h = (float)((n >> 5) & 31), w = (float)(n & 31);
  const float* tbp = tb + ((size_t)b * N_ + n) * 3;
  float tx = (d + tbp[0]) * 0.75f;
  float ty = (h + tbp[1]) * 0.78125f;
  float tz = (w + tbp[2]) * 0.78125f;
  const float4* alive = alivePosG + (size_t)pair * N_;
  int m;
  if (pair & 1) m = match_ball<1>(alive, n, tx, ty, tz, cut2);
  else          m = match_ball<2>(alive, n, tx, ty, tz, cut2);
  m &= isC;
  atomicAdd(&s_tp, m);
  atomicAdd(&s_t, isC);
  __syncthreads();
  if (threadIdx.x == 0) {
    atomicAdd(&out[pair * 3 + 0], s_tp);
    atomicAdd(&out[pair * 3 + 1], -s_tp);
    atomicAdd(&out[pair * 3 + 2], s_t - s_tp);
  }
}

// ------------------------------------------------------------------------------
extern "C" void kernel_launch(void* const* d_in, const int* in_sizes, int n_in,
                              void* d_out, int out_size, void* d_ws, size_t ws_size,
                              hipStream_t stream) {
  (void)in_sizes; (void)n_in; (void)out_size; (void)ws_size;
  const float* pc = (const float*)d_in[0];  // pred_clses (B,3,4,32,32) f32
  const float* pb = (const float*)d_in[1];  // pred_boxes (B,3,4,32,32) f32
  const int*   tc = (const int*)d_in[2];    // targ_clses (B,4,32,32) i32
  const float* tb = (const float*)d_in[3];  // targ_boxes (B,4,32,32,3) f32
  int* out = (int*)d_out;                   // (B, C-1, 1, 3) int32 counts

  char* ws = (char*)d_ws;
  size_t off = 0;
  auto alloc = [&](size_t bytes) -> void* {
    void* p = ws + off;
    off += (bytes + 255) & ~(size_t)255;
    return p;
  };
  int*    Mcnt      = (int*)alloc(4 * 4);
  float4* posG      = (float4*)alloc((size_t)4 * N_ * 16);
  u16*    slotG     = (u16*)alloc((size_t)4 * N_ * 2);
  float4* sp4       = (float4*)alloc((size_t)4 * MMAX_ * 16);
  int*    deg       = (int*)alloc((size_t)4 * MMAX_ * 4);
  u16*    predL     = (u16*)alloc((size_t)4 * MMAX_ * KCAP_ * 2);
  float4* alivePosG = (float4*)alloc((size_t)4 * N_ * 16);

  k_compact<<<4, 1024, 0, stream>>>(pc, pb, Mcnt, posG, slotG, sp4, alivePosG);
  k_adj<<<(4 * N_) / 256, 256, 0, stream>>>(posG, slotG, deg, predL);
  k_nms<<<4, 1024, 0, stream>>>(Mcnt, deg, predL, sp4, alivePosG, out);
  k_match<<<(4 * N_) / 256, 256, 0, stream>>>(alivePosG, tc, tb, out);
}

// Round 11
// 102.426 us; speedup vs baseline: 1.5137x; 1.0225x over previous
//
#include <hip/hip_runtime.h>
#include <cstdint>
#include <cstddef>

typedef unsigned long long u64;
typedef unsigned int u32;
typedef unsigned short u16;

#define N_ 4096
#define KCAP_ 32     // pred-list cap; geometric ball bound => max deg ~20
#define SENT_ 4096   // sentinel pred index -> always-dead byte slot

__device__ __forceinline__ float sigf(float x) { return 1.0f / (1.0f + expf(-x)); }

// any-of-4 over byte array; wa/wb are u32s each packing two u16 indices
#define ANY4B(arr, wa, wb) \
  ((int)((arr)[(wa) & 0xFFFFu] | (arr)[(wa) >> 16] | \
         (arr)[(wb) & 0xFFFFu] | (arr)[(wb) >> 16]))

// ---------------- ball pred-scan from LDS halo tile (logic verified R6-R10) ---
// Geometric pruning (offsets in open (0,1)):
//   cut=1.0 : two axes at |dcell|=2 give min d2 >= 1.17 > 1.0  -> 80-cell ball
//   cut=0.75: any axis at |dcell|=2 exceeds 0.75 strictly      -> 26-cell ball
// pred(i,j): dist<cut && (okey_i > okey_j || (okey_i==okey_j && n_i < n_j))
// == "i earlier in ref's stable desc-conf sort" (key orientation, label-free).
template <int EXT>
__device__ __forceinline__ int build_preds(
    const float4* __restrict__ hp, float4 self, int d0, int hl, int wl, int n,
    float cut2, u16* __restrict__ rowp) {
  u32 okey = __float_as_uint(self.w);
  int cnt = 0;
  #pragma unroll
  for (int dd = -EXT; dd <= EXT; ++dd) {
    #pragma unroll
    for (int dh = -EXT; dh <= EXT; ++dh) {
      #pragma unroll
      for (int dw = -EXT; dw <= EXT; ++dw) {
        if (dd == 0 && dh == 0 && dw == 0) continue;
        if ((dd * dd == 4) + (dh * dh == 4) + (dw * dw == 4) > 1) continue;
        int d2 = d0 + dd;
        if ((u32)d2 >= 4u) continue;           // d has no halo; h/w halo'd in LDS
        float4 pn = hp[d2 * 144 + (hl + dh) * 12 + (wl + dw)];  // dead -> 1e9
        float dx = pn.x - self.x, dy = pn.y - self.y, dz = pn.z - self.z;
        float dsq = dx * dx + dy * dy + dz * dz;
        u32 ok2 = __float_as_uint(pn.w);
        int n2 = n + (dd << 10) + (dh << 5) + dw;  // correct whenever pn alive
        bool pred = (dsq < cut2) && (ok2 > okey || (ok2 == okey && n2 < n));
        if (pred) {                              // rare (~2 per row)
          if (cnt < KCAP_) rowp[cnt] = (u16)n2;
          cnt++;
        }
      }
    }
  }
  return cnt;
}

// ---------------- K1: fused compact+adjacency, tile+halo ----------------------
// 16 blocks per pair; block owns a 4(d)x8x8 anchor tile. Computes the 4x12x12
// halo region (conf/argmax/okey/sigmoid-pos) into LDS (2.25x redundant compute,
// no inter-block dependency), then per interior anchor writes dense posG
// (w=okey, dead=1e9) and the anchor-indexed pred list. No compaction: the NMS
// fixpoint is label-invariant, so anchor indices serve as row ids directly.
__global__ __launch_bounds__(256) void k_build(
    const float* __restrict__ pc, const float* __restrict__ pb,
    float4* __restrict__ posG, int* __restrict__ deg, u16* __restrict__ predL) {
  int blk = blockIdx.x;
  int pair = blk >> 4, tile = blk & 15;
  int b = pair >> 1, c = (pair & 1) + 1;
  int th0 = ((tile >> 2) << 3);   // 0,8,16,24
  int tw0 = ((tile & 3) << 3);
  __shared__ float4 hpos[576];    // 4 x 12 x 12 halo region
  const float* pcb = pc + (size_t)b * 3 * N_;
  const float* pbb = pb + (size_t)b * 3 * N_;
  for (int e = threadIdx.x; e < 576; e += 256) {
    int d = e / 144, rem = e - d * 144;
    int hh = rem / 12, ww = rem - hh * 12;
    int h = th0 + hh - 2, w = tw0 + ww - 2;
    float4 v; v.x = 1e9f; v.y = 1e9f; v.z = 1e9f; v.w = 0.f;
    if ((u32)h < 32u && (u32)w < 32u) {
      int n = (d << 10) | (h << 5) | w;
      float v0 = pcb[n], v1 = pcb[n + N_], v2 = pcb[n + 2 * N_];
      float cf = v0; int a = 0;
      if (v1 > cf) { cf = v1; a = 1; }
      if (v2 > cf) { cf = v2; a = 2; }
      if (a == c) {
        u32 o = __float_as_uint(cf);
        o ^= (o >> 31) ? 0xFFFFFFFFu : 0x80000000u;   // ascending-orderable conf
        // (g+s)/dims*REAL == (g+s)*{0.75,0.78125,0.78125} bit-exact (pow2 dims)
        v.x = ((float)d + sigf(pbb[n])) * 0.75f;
        v.y = ((float)h + sigf(pbb[n + N_])) * 0.78125f;
        v.z = ((float)w + sigf(pbb[n + 2 * N_])) * 0.78125f;
        v.w = __uint_as_float(o);
      }
    }
    hpos[e] = v;
  }
  __syncthreads();
  // interior pass: one thread per anchor of the tile
  int tid = threadIdx.x;
  int d0 = tid >> 6;              // 0..3
  int hl = ((tid >> 3) & 7) + 2;  // 2..9 (local, halo offset)
  int wl = (tid & 7) + 2;
  int n = (d0 << 10) | ((th0 + hl - 2) << 5) | (tw0 + wl - 2);
  float4 self = hpos[d0 * 144 + hl * 12 + wl];
  posG[pair * N_ + n] = self;
  u16* rowp = predL + (((size_t)(pair * N_ + n)) << 5);
  int cnt = 0;
  if (self.x < 1e8f) {
    if (pair & 1) cnt = build_preds<1>(hpos, self, d0, hl, wl, n, 0.5625f, rowp);
    else          cnt = build_preds<2>(hpos, self, d0, hl, wl, n, 1.0f, rowp);
    if (cnt > KCAP_) cnt = KCAP_;
  }
  deg[pair * N_ + n] = cnt;
  int pad = (cnt + 3) & ~3;       // pad group-of-4 with sentinel
  for (int s = cnt; s < pad; ++s) rowp[s] = (u16)SENT_;
}

// ---------------- K2: anchor-indexed byte-array LDS NMS fixpoint --------------
// Per-iteration exactly the ref update:
//   free_i  = alive_i && no alive conflicting predecessor
//   alive'_j = alive_j && no free conflicting predecessor
// Monotone => early break at fixpoint exact; capped at ref's 32 iters.
// 4 rows/thread; 16B/row fast path (dg<=8), dg>8 tail reads L2-hot predL.
// Epilogue writes alivePosG for EVERY anchor (alive ? pos : dead) + count.
__global__ __launch_bounds__(1024) void k_nms(
    const float4* __restrict__ posG, const int* __restrict__ deg,
    const u16* __restrict__ predL,
    float4* __restrict__ alivePosG, int* __restrict__ out) {
  int pair = blockIdx.x, tid = threadIdx.x;
  __shared__ unsigned char aliveB[4112];  // [4096..] sentinel slots, always 0
  __shared__ unsigned char freeB[4112];
  __shared__ int flag[2], acnt;
  float4 pos[4]; int dg[4]; u32 pw[4][4]; bool al[4];
  #pragma unroll
  for (int q = 0; q < 4; ++q) {
    int r = tid + (q << 10);
    pos[q] = posG[pair * N_ + r];
    al[q] = (pos[q].x < 1e8f);
    dg[q] = deg[pair * N_ + r];
    uint4 t = *(const uint4*)(predL + (((size_t)(pair * N_ + r)) << 5));
    pw[q][0] = t.x; pw[q][1] = t.y; pw[q][2] = t.z; pw[q][3] = t.w;
    aliveB[r] = al[q];
    freeB[r] = 0;
  }
  if (tid < 16) { aliveB[4096 + tid] = 0; freeB[4096 + tid] = 0; }
  if (tid == 0) { flag[0] = 0; flag[1] = 0; acnt = 0; }
  __syncthreads();

  for (int iter = 0; iter < 32; ++iter) {
    if (tid == 0) flag[(iter + 1) & 1] = 0;  // reset NEXT flag (barrier-ordered)
    // ---- stage 1: free = alive && all preds dead
    #pragma unroll
    for (int q = 0; q < 4; ++q) {
      int r = tid + (q << 10);
      bool fr = al[q];
      if (al[q] && dg[q]) {
        int any = ANY4B(aliveB, pw[q][0], pw[q][1]);
        if (dg[q] > 4) any |= ANY4B(aliveB, pw[q][2], pw[q][3]);
        if (dg[q] > 8) {                     // rare tail, L2-hot
          const u16* rowp = predL + (((size_t)(pair * N_ + r)) << 5);
          for (int k = 8; k < dg[q]; ++k) any |= aliveB[rowp[k]];
        }
        fr = (any == 0);
      }
      freeB[r] = fr;
    }
    __syncthreads();
    // ---- stage 2: alive' = alive && no free pred (monotone: only 1->0)
    int lch = 0;
    #pragma unroll
    for (int q = 0; q < 4; ++q) {
      int r = tid + (q << 10);
      if (al[q] && dg[q]) {
        int any = ANY4B(freeB, pw[q][0], pw[q][1]);
        if (dg[q] > 4) any |= ANY4B(freeB, pw[q][2], pw[q][3]);
        if (dg[q] > 8) {
          const u16* rowp = predL + (((size_t)(pair * N_ + r)) << 5);
          for (int k = 8; k < dg[q]; ++k) any |= freeB[rowp[k]];
        }
        if (any) { al[q] = false; aliveB[r] = 0; lch = 1; }
      }
    }
    if (lch) flag[iter & 1] = 1;
    __syncthreads();
    if (!flag[iter & 1]) break;              // fixpoint: rest are no-ops
  }

  // epilogue: dense alive map + count
  float4 dead; dead.x = 1e9f; dead.y = 1e9f; dead.z = 1e9f; dead.w = 0.f;
  #pragma unroll
  for (int q = 0; q < 4; ++q) {
    int r = tid + (q << 10);
    alivePosG[pair * N_ + r] = al[q] ? pos[q] : dead;
    u64 ball = __ballot(al[q]);
    if ((tid & 63) == 0 && ball) atomicAdd(&acnt, __popcll(ball));
  }
  __syncthreads();
  if (tid == 0) {
    out[pair * 3 + 0] = 0;        // tp  (K3 adds)
    out[pair * 3 + 1] = acnt;     // fp = A - tp (K3 subtracts)
    out[pair * 3 + 2] = 0;        // fn = t_cls - tp (K3 adds/subtracts)
  }
}

// ---------------- K3: lattice-ball target matching (verified R8/R10) ----------
// One thread per anchor; a matching alive pred lies within the same +/-2 ball
// (target offset in [0,1), pred offset in (0,1)); includes the center cell.
template <int EXT>
__device__ __forceinline__ int match_ball(
    const float4* __restrict__ alive, int n, float tx, float ty, float tz,
    float cut2) {
  int d0 = n >> 10, h0 = (n >> 5) & 31, w0 = n & 31;
  int m = 0;
  #pragma unroll
  for (int dd = -EXT; dd <= EXT; ++dd) {
    #pragma unroll
    for (int dh = -EXT; dh <= EXT; ++dh) {
      #pragma unroll
      for (int dw = -EXT; dw <= EXT; ++dw) {
        if ((dd * dd == 4) + (dh * dh == 4) + (dw * dw == 4) > 1) continue;
        int d2i = d0 + dd, h2i = h0 + dh, w2i = w0 + dw;
        if ((u32)d2i < 4u && (u32)h2i < 32u && (u32)w2i < 32u) {
          int n2 = (d2i << 10) | (h2i << 5) | w2i;
          float4 p = alive[n2];               // dead -> 1e9 -> dist rejects
          float dx = p.x - tx, dy = p.y - ty, dz = p.z - tz;
          m |= (int)(dx * dx + dy * dy + dz * dz < cut2);
        }
      }
    }
  }
  return m;
}

__global__ __launch_bounds__(256) void k_match(
    const float4* __restrict__ alivePosG,
    const int* __restrict__ tcls, const float* __restrict__ tb,
    int* __restrict__ out) {
  int idx = blockIdx.x * 256 + threadIdx.x;   // 0..16383
  int pair = idx >> 12, n = idx & (N_ - 1);
  int b = pair >> 1, c = (pair & 1) + 1;
  float cut2 = (pair & 1) ? 0.5625f : 1.0f;
  __shared__ int s_tp, s_t;
  if (threadIdx.x == 0) { s_tp = 0; s_t = 0; }
  __syncthreads();
  int isC = (tcls[b * N_ + n] == c) ? 1 : 0;
  float d = (float)(n >> 10), h = (float)((n >> 5) & 31), w = (float)(n & 31);
  const float* tbp = tb + ((size_t)b * N_ + n) * 3;
  float tx = (d + tbp[0]) * 0.75f;
  float ty = (h + tbp[1]) * 0.78125f;
  float tz = (w + tbp[2]) * 0.78125f;
  const float4* alive = alivePosG + (size_t)pair * N_;
  int m;
  if (pair & 1) m = match_ball<1>(alive, n, tx, ty, tz, cut2);
  else          m = match_ball<2>(alive, n, tx, ty, tz, cut2);
  m &= isC;
  atomicAdd(&s_tp, m);
  atomicAdd(&s_t, isC);
  __syncthreads();
  if (threadIdx.x == 0) {
    atomicAdd(&out[pair * 3 + 0], s_tp);
    atomicAdd(&out[pair * 3 + 1], -s_tp);
    atomicAdd(&out[pair * 3 + 2], s_t - s_tp);
  }
}

// ------------------------------------------------------------------------------
extern "C" void kernel_launch(void* const* d_in, const int* in_sizes, int n_in,
                              void* d_out, int out_size, void* d_ws, size_t ws_size,
                              hipStream_t stream) {
  (void)in_sizes; (void)n_in; (void)out_size; (void)ws_size;
  const float* pc = (const float*)d_in[0];  // pred_clses (B,3,4,32,32) f32
  const float* pb = (const float*)d_in[1];  // pred_boxes (B,3,4,32,32) f32
  const int*   tc = (const int*)d_in[2];    // targ_clses (B,4,32,32) i32
  const float* tb = (const float*)d_in[3];  // targ_boxes (B,4,32,32,3) f32
  int* out = (int*)d_out;                   // (B, C-1, 1, 3) int32 counts

  char* ws = (char*)d_ws;
  size_t off = 0;
  auto alloc = [&](size_t bytes) -> void* {
    void* p = ws + off;
    off += (bytes + 255) & ~(size_t)255;
    return p;
  };
  float4* posG      = (float4*)alloc((size_t)4 * N_ * 16);
  int*    deg       = (int*)alloc((size_t)4 * N_ * 4);
  u16*    predL     = (u16*)alloc((size_t)4 * N_ * KCAP_ * 2);
  float4* alivePosG = (float4*)alloc((size_t)4 * N_ * 16);

  k_build<<<64, 256, 0, stream>>>(pc, pb, posG, deg, predL);
  k_nms<<<4, 1024, 0, stream>>>(posG, deg, predL, alivePosG, out);
  k_match<<<64, 256, 0, stream>>>(alivePosG, tc, tb, out);
}